// Round 1
// baseline (644.024 us; speedup 1.0000x reference)
//
#include <hip/hip_runtime.h>
#include <hip/hip_bf16.h>

// Problem constants (B=8, L=4096, D=1024, S=256)
#define BB 8
#define LL 4096
#define DD 1024
#define SS 256
#define NTOK (BB * LL)  // 32768 tokens

typedef short bf16x8 __attribute__((ext_vector_type(8)));
typedef float f32x4 __attribute__((ext_vector_type(4)));

// ---------------------------------------------------------------------------
// Kernel 1: RMSNorm + bf16 cast.  One block per token row (D=1024).
// xn[i,k] = bf16( x[i,k] * w_norm[k] * rsqrt(mean(x^2)+eps) )
// ---------------------------------------------------------------------------
__global__ __launch_bounds__(256) void prep_rms(const float* __restrict__ x,
                                                const float* __restrict__ wn,
                                                __hip_bfloat16* __restrict__ xn) {
  const size_t row = blockIdx.x;
  const int t = threadIdx.x;
  const float4 xv = reinterpret_cast<const float4*>(x + row * DD)[t];
  const float4 wv = reinterpret_cast<const float4*>(wn)[t];
  float ss = xv.x * xv.x + xv.y * xv.y + xv.z * xv.z + xv.w * xv.w;
#pragma unroll
  for (int m = 32; m >= 1; m >>= 1) ss += __shfl_xor(ss, m);
  __shared__ float red[4];
  if ((t & 63) == 0) red[t >> 6] = ss;
  __syncthreads();
  const float tot = red[0] + red[1] + red[2] + red[3];
  const float r = rsqrtf(tot * (1.0f / DD) + 1e-8f);
  union { ushort4 u; __hip_bfloat16 h[4]; } o;
  o.h[0] = __float2bfloat16(xv.x * wv.x * r);
  o.h[1] = __float2bfloat16(xv.y * wv.y * r);
  o.h[2] = __float2bfloat16(xv.z * wv.z * r);
  o.h[3] = __float2bfloat16(xv.w * wv.w * r);
  reinterpret_cast<ushort4*>(xn + row * DD)[t] = o.u;
}

// ---------------------------------------------------------------------------
// Kernel 2: weight convert f32 -> bf16 with transpose.  WT[n*K+k] = W[k*Nw+n]
// ---------------------------------------------------------------------------
__global__ __launch_bounds__(256) void convT(const float* __restrict__ W,
                                             __hip_bfloat16* __restrict__ WT,
                                             int K, int Nw) {
  const int idx = blockIdx.x * 256 + threadIdx.x;
  if (idx >= K * Nw) return;
  const int k = idx / Nw, n = idx % Nw;
  WT[(size_t)n * K + k] = __float2bfloat16(W[idx]);
}

// ---------------------------------------------------------------------------
// Kernel 3: bf16 MFMA GEMM.  C[M,Nt] = epi(A[M,K] @ BT[Nt,K]^T + bias)
// 128x128 tile, 4 waves (2x2 of 64x64), BK=64, reg-staged LDS, +8 pad.
// EPI: 0 = bf16 out, 1 = tanh->bf16, 2 = sigmoid->bf16, 3 = +resid -> f32
// ---------------------------------------------------------------------------
template <int EPI>
__global__ __launch_bounds__(256) void gemm_bf16(
    const __hip_bfloat16* __restrict__ A, int lda,
    const __hip_bfloat16* __restrict__ BT,  // [Nt][K] (pre-transposed)
    const float* __restrict__ bias,
    void* __restrict__ Cptr, int ldc,
    const float* __restrict__ resid,
    int M, int Nt, int K) {
  __shared__ __align__(16) __hip_bfloat16 As[128][72];
  __shared__ __align__(16) __hip_bfloat16 Bs[128][72];

  const int t = threadIdx.x;
  const int bm = blockIdx.x, bn = blockIdx.y;
  const int wave = t >> 6, lane = t & 63;
  const int wr = (wave >> 1) * 64;  // wave row offset in tile
  const int wc = (wave & 1) * 64;   // wave col offset in tile
  const int lr = lane & 15;         // row (A) / col (B) within fragment
  const int kg = lane >> 4;         // k-group 0..3

  const int tr = t >> 3;          // staging row 0..31 (per pass)
  const int tc = (t & 7) * 8;     // staging col (8 bf16 = 16B)

  f32x4 acc[4][4] = {};

  for (int k0 = 0; k0 < K; k0 += 64) {
    __syncthreads();
#pragma unroll
    for (int p = 0; p < 4; ++p) {
      const int r = p * 32 + tr;
      const int4 va = *reinterpret_cast<const int4*>(
          A + (size_t)(bm * 128 + r) * lda + k0 + tc);
      *reinterpret_cast<int4*>(&As[r][tc]) = va;
      const int4 vb = *reinterpret_cast<const int4*>(
          BT + (size_t)(bn * 128 + r) * K + k0 + tc);
      *reinterpret_cast<int4*>(&Bs[r][tc]) = vb;
    }
    __syncthreads();
#pragma unroll
    for (int kk = 0; kk < 64; kk += 32) {
      bf16x8 af[4], bfr[4];
#pragma unroll
      for (int m = 0; m < 4; ++m)
        af[m] = *reinterpret_cast<const bf16x8*>(&As[wr + m * 16 + lr][kk + kg * 8]);
#pragma unroll
      for (int n = 0; n < 4; ++n)
        bfr[n] = *reinterpret_cast<const bf16x8*>(&Bs[wc + n * 16 + lr][kk + kg * 8]);
#pragma unroll
      for (int m = 0; m < 4; ++m)
#pragma unroll
        for (int n = 0; n < 4; ++n)
          acc[m][n] = __builtin_amdgcn_mfma_f32_16x16x32_bf16(af[m], bfr[n],
                                                              acc[m][n], 0, 0, 0);
    }
  }

  // Epilogue.  C/D layout: col = lane&15, row = (lane>>4)*4 + j  [m89/m91]
  const int rowb = bm * 128 + wr + kg * 4;
  const int colb = bn * 128 + wc + lr;
#pragma unroll
  for (int m = 0; m < 4; ++m) {
#pragma unroll
    for (int n = 0; n < 4; ++n) {
      const int col = colb + n * 16;
      const float bv = bias[col];
#pragma unroll
      for (int j = 0; j < 4; ++j) {
        const int row = rowb + m * 16 + j;
        float v = acc[m][n][j] + bv;
        if (EPI == 0) {
          ((__hip_bfloat16*)Cptr)[(size_t)row * ldc + col] = __float2bfloat16(v);
        } else if (EPI == 1) {
          ((__hip_bfloat16*)Cptr)[(size_t)row * ldc + col] = __float2bfloat16(tanhf(v));
        } else if (EPI == 2) {
          ((__hip_bfloat16*)Cptr)[(size_t)row * ldc + col] =
              __float2bfloat16(1.0f / (1.0f + expf(-v)));
        } else {
          const size_t off = (size_t)row * ldc + col;
          ((float*)Cptr)[off] = v + resid[off];
        }
      }
    }
  }
}

// ---------------------------------------------------------------------------
// Kernel 4: sequential gated recurrence + output gate.
// One lane per (b, s) channel; 32 blocks x 64 lanes; 8-token chunks in regs.
// h_t = (1-dt)*h + dt*u = h + dt*(u-h);  hsg = h * sigmoid(g)   (in-place over ut)
// ---------------------------------------------------------------------------
__global__ __launch_bounds__(64) void scan_kernel(
    const __hip_bfloat16* __restrict__ ut,
    const __hip_bfloat16* __restrict__ dtb,
    const __hip_bfloat16* __restrict__ gz,   // uzg + 512, row stride 768
    __hip_bfloat16* __restrict__ hsg) {
  const int b = blockIdx.x >> 2;
  const int c = ((blockIdx.x & 3) * 64) + threadIdx.x;
  const size_t tb = (size_t)b * LL;
  float h = 0.0f;
  for (int t0 = 0; t0 < LL; t0 += 8) {
    float u[8], d[8], g[8];
#pragma unroll
    for (int q = 0; q < 8; ++q) {
      const size_t rowq = tb + t0 + q;
      u[q] = __bfloat162float(ut[rowq * SS + c]);
      d[q] = __bfloat162float(dtb[rowq * SS + c]);
      g[q] = __bfloat162float(gz[rowq * 768 + c]);
    }
    __hip_bfloat16 o[8];
#pragma unroll
    for (int q = 0; q < 8; ++q) {
      h = fmaf(d[q], u[q] - h, h);
      o[q] = __float2bfloat16(h / (1.0f + expf(-g[q])));
    }
#pragma unroll
    for (int q = 0; q < 8; ++q) hsg[(tb + t0 + q) * SS + c] = o[q];
  }
}

// ---------------------------------------------------------------------------
extern "C" void kernel_launch(void* const* d_in, const int* in_sizes, int n_in,
                              void* d_out, int out_size, void* d_ws, size_t ws_size,
                              hipStream_t stream) {
  const float* x      = (const float*)d_in[0];
  const float* w_norm = (const float*)d_in[1];
  const float* W_in   = (const float*)d_in[2];
  const float* b_in   = (const float*)d_in[3];
  const float* W_x    = (const float*)d_in[4];
  const float* b_x    = (const float*)d_in[5];
  const float* W_dt   = (const float*)d_in[6];
  const float* b_dt   = (const float*)d_in[7];
  const float* W_out  = (const float*)d_in[8];
  const float* b_out  = (const float*)d_in[9];
  float* out = (float*)d_out;

  // Workspace layout (bf16 buffers). ut/dt alias the dead xn region.
  char* w = (char*)d_ws;
  __hip_bfloat16* xn  = (__hip_bfloat16*)w;                 // NTOK*1024
  __hip_bfloat16* ut  = (__hip_bfloat16*)w;                 // NTOK*256 (after GEMM1)
  __hip_bfloat16* dtb = (__hip_bfloat16*)(w + (size_t)NTOK * SS * 2);
  w += (size_t)NTOK * DD * 2;                               // 64 MiB
  __hip_bfloat16* uzg = (__hip_bfloat16*)w;  w += (size_t)NTOK * 768 * 2;  // 48 MiB
  __hip_bfloat16* WinT  = (__hip_bfloat16*)w;  w += (size_t)768 * DD * 2;
  __hip_bfloat16* WxT   = (__hip_bfloat16*)w;  w += (size_t)SS * SS * 2;
  __hip_bfloat16* WdtT  = (__hip_bfloat16*)w;  w += (size_t)SS * SS * 2;
  __hip_bfloat16* WoutT = (__hip_bfloat16*)w;  w += (size_t)DD * SS * 2;
  (void)ws_size; (void)n_in; (void)in_sizes; (void)out_size;

  // Stage 0: weight conversion (pre-transposed bf16)
  convT<<<(DD * 768 + 255) / 256, 256, 0, stream>>>(W_in, WinT, DD, 768);
  convT<<<(SS * SS + 255) / 256, 256, 0, stream>>>(W_x, WxT, SS, SS);
  convT<<<(SS * SS + 255) / 256, 256, 0, stream>>>(W_dt, WdtT, SS, SS);
  convT<<<(SS * DD + 255) / 256, 256, 0, stream>>>(W_out, WoutT, SS, DD);

  // Stage 1: RMSNorm -> xn (bf16)
  prep_rms<<<NTOK, 256, 0, stream>>>(x, w_norm, xn);

  // Stage 2: uzg = xn @ W_in + b_in   (M=32768, N=768, K=1024)
  gemm_bf16<0><<<dim3(NTOK / 128, 768 / 128), 256, 0, stream>>>(
      xn, DD, WinT, b_in, uzg, 768, nullptr, NTOK, 768, DD);

  // Stage 3: ut = tanh(u @ W_x + b_x); dt = sigmoid(z @ W_dt + b_dt)
  gemm_bf16<1><<<dim3(NTOK / 128, SS / 128), 256, 0, stream>>>(
      uzg, 768, WxT, b_x, ut, SS, nullptr, NTOK, SS, SS);
  gemm_bf16<2><<<dim3(NTOK / 128, SS / 128), 256, 0, stream>>>(
      uzg + SS, 768, WdtT, b_dt, dtb, SS, nullptr, NTOK, SS, SS);

  // Stage 4: recurrence + gate (in-place hsg over ut buffer)
  scan_kernel<<<BB * 4, 64, 0, stream>>>(ut, dtb, uzg + 2 * SS, ut);

  // Stage 5: out = x + hsg @ W_out + b_out  (M=32768, N=1024, K=256)
  gemm_bf16<3><<<dim3(NTOK / 128, DD / 128), 256, 0, stream>>>(
      ut, SS, WoutT, b_out, out, DD, x, NTOK, DD, SS);
}

// Round 3
// 288.218 us; speedup vs baseline: 2.2345x; 2.2345x over previous
//
#include <hip/hip_runtime.h>
#include <hip/hip_bf16.h>

// Problem constants (B=8, L=4096, D=1024, S=256)
#define BB 8
#define LL 4096
#define DD 1024
#define SS 256
#define NTOK (BB * LL)  // 32768 tokens
#define CCH 64          // chunks per sequence (parallel scan)
#define TCH (LL / CCH)  // 64 timesteps per chunk

typedef short bf16x8 __attribute__((ext_vector_type(8)));
typedef float f32x4 __attribute__((ext_vector_type(4)));

__device__ __forceinline__ float bfu(unsigned short v) {
  union { unsigned int i; float f; } x;
  x.i = ((unsigned int)v) << 16;
  return x.f;
}

// ---------------------------------------------------------------------------
// Kernel 1: RMSNorm + bf16 cast.  One block per token row (D=1024).
// ---------------------------------------------------------------------------
__global__ __launch_bounds__(256) void prep_rms(const float* __restrict__ x,
                                                const float* __restrict__ wn,
                                                __hip_bfloat16* __restrict__ xn) {
  const size_t row = blockIdx.x;
  const int t = threadIdx.x;
  const float4 xv = reinterpret_cast<const float4*>(x + row * DD)[t];
  const float4 wv = reinterpret_cast<const float4*>(wn)[t];
  float ss = xv.x * xv.x + xv.y * xv.y + xv.z * xv.z + xv.w * xv.w;
#pragma unroll
  for (int m = 32; m >= 1; m >>= 1) ss += __shfl_xor(ss, m);
  __shared__ float red[4];
  if ((t & 63) == 0) red[t >> 6] = ss;
  __syncthreads();
  const float tot = red[0] + red[1] + red[2] + red[3];
  const float r = rsqrtf(tot * (1.0f / DD) + 1e-8f);
  union { ushort4 u; __hip_bfloat16 h[4]; } o;
  o.h[0] = __float2bfloat16(xv.x * wv.x * r);
  o.h[1] = __float2bfloat16(xv.y * wv.y * r);
  o.h[2] = __float2bfloat16(xv.z * wv.z * r);
  o.h[3] = __float2bfloat16(xv.w * wv.w * r);
  reinterpret_cast<ushort4*>(xn + row * DD)[t] = o.u;
}

// ---------------------------------------------------------------------------
// Kernel 2: weight convert f32 -> bf16 with transpose.  WT[n*K+k] = W[k*Nw+n]
// ---------------------------------------------------------------------------
__global__ __launch_bounds__(256) void convT(const float* __restrict__ W,
                                             __hip_bfloat16* __restrict__ WT,
                                             int K, int Nw) {
  const int idx = blockIdx.x * 256 + threadIdx.x;
  if (idx >= K * Nw) return;
  const int k = idx / Nw, n = idx % Nw;
  WT[(size_t)n * K + k] = __float2bfloat16(W[idx]);
}

// ---------------------------------------------------------------------------
// Kernel 3: bf16 MFMA GEMM.  C[M,Nt] = epi(A[M,K] @ BT[Nt,K]^T + bias)
// 128x128 tile, 4 waves (2x2 of 64x64), BK=64, reg-staged LDS, +8 pad.
// EPI: 0 = bf16 out, 1 = tanh->bf16, 2 = sigmoid->bf16, 3 = +resid -> f32
// ---------------------------------------------------------------------------
template <int EPI>
__global__ __launch_bounds__(256) void gemm_bf16(
    const __hip_bfloat16* __restrict__ A, int lda,
    const __hip_bfloat16* __restrict__ BT,  // [Nt][K] (pre-transposed)
    const float* __restrict__ bias,
    void* __restrict__ Cptr, int ldc,
    const float* __restrict__ resid,
    int M, int Nt, int K) {
  __shared__ __align__(16) __hip_bfloat16 As[128][72];
  __shared__ __align__(16) __hip_bfloat16 Bs[128][72];

  const int t = threadIdx.x;
  const int bm = blockIdx.x, bn = blockIdx.y;
  const int wave = t >> 6, lane = t & 63;
  const int wr = (wave >> 1) * 64;
  const int wc = (wave & 1) * 64;
  const int lr = lane & 15;
  const int kg = lane >> 4;

  const int tr = t >> 3;
  const int tc = (t & 7) * 8;

  f32x4 acc[4][4] = {};

  for (int k0 = 0; k0 < K; k0 += 64) {
    __syncthreads();
#pragma unroll
    for (int p = 0; p < 4; ++p) {
      const int r = p * 32 + tr;
      const int4 va = *reinterpret_cast<const int4*>(
          A + (size_t)(bm * 128 + r) * lda + k0 + tc);
      *reinterpret_cast<int4*>(&As[r][tc]) = va;
      const int4 vb = *reinterpret_cast<const int4*>(
          BT + (size_t)(bn * 128 + r) * K + k0 + tc);
      *reinterpret_cast<int4*>(&Bs[r][tc]) = vb;
    }
    __syncthreads();
#pragma unroll
    for (int kk = 0; kk < 64; kk += 32) {
      bf16x8 af[4], bfr[4];
#pragma unroll
      for (int m = 0; m < 4; ++m)
        af[m] = *reinterpret_cast<const bf16x8*>(&As[wr + m * 16 + lr][kk + kg * 8]);
#pragma unroll
      for (int n = 0; n < 4; ++n)
        bfr[n] = *reinterpret_cast<const bf16x8*>(&Bs[wc + n * 16 + lr][kk + kg * 8]);
#pragma unroll
      for (int m = 0; m < 4; ++m)
#pragma unroll
        for (int n = 0; n < 4; ++n)
          acc[m][n] = __builtin_amdgcn_mfma_f32_16x16x32_bf16(af[m], bfr[n],
                                                              acc[m][n], 0, 0, 0);
    }
  }

  // Epilogue.  C/D layout: col = lane&15, row = (lane>>4)*4 + j  [m89/m91]
  const int rowb = bm * 128 + wr + kg * 4;
  const int colb = bn * 128 + wc + lr;
#pragma unroll
  for (int m = 0; m < 4; ++m) {
#pragma unroll
    for (int n = 0; n < 4; ++n) {
      const int col = colb + n * 16;
      const float bv = bias[col];
#pragma unroll
      for (int j = 0; j < 4; ++j) {
        const int row = rowb + m * 16 + j;
        float v = acc[m][n][j] + bv;
        if (EPI == 0) {
          ((__hip_bfloat16*)Cptr)[(size_t)row * ldc + col] = __float2bfloat16(v);
        } else if (EPI == 1) {
          ((__hip_bfloat16*)Cptr)[(size_t)row * ldc + col] = __float2bfloat16(tanhf(v));
        } else if (EPI == 2) {
          ((__hip_bfloat16*)Cptr)[(size_t)row * ldc + col] =
              __float2bfloat16(1.0f / (1.0f + expf(-v)));
        } else {
          const size_t off = (size_t)row * ldc + col;
          ((float*)Cptr)[off] = v + resid[off];
        }
      }
    }
  }
}

// ---------------------------------------------------------------------------
// Kernel 4a: chunked scan phase A.  Per (b, chunk, s): local scan from h=0
// giving h0, and decay product A = prod(1-d).  2 channels per lane (ushort2).
// ---------------------------------------------------------------------------
__global__ __launch_bounds__(128) void scan_phase_a(
    const __hip_bfloat16* __restrict__ ut,
    const __hip_bfloat16* __restrict__ dtb,
    float* __restrict__ h0s, float* __restrict__ As) {
  const int bc = blockIdx.x;             // b*CCH + c
  const int b = bc / CCH, c = bc % CCH;
  const int ch = threadIdx.x * 2;        // channel pair base
  const size_t base = ((size_t)b * LL + (size_t)c * TCH) * SS + ch;
  float h0 = 0.f, h1 = 0.f, A0 = 1.f, A1 = 1.f;
#pragma unroll 8
  for (int t = 0; t < TCH; ++t) {
    const ushort2 uu = *reinterpret_cast<const ushort2*>(ut + base + (size_t)t * SS);
    const ushort2 dd = *reinterpret_cast<const ushort2*>(dtb + base + (size_t)t * SS);
    const float d0 = bfu(dd.x), d1 = bfu(dd.y);
    h0 = fmaf(d0, bfu(uu.x) - h0, h0);
    h1 = fmaf(d1, bfu(uu.y) - h1, h1);
    A0 *= (1.f - d0);
    A1 *= (1.f - d1);
  }
  const size_t o = (size_t)bc * SS + ch;
  *reinterpret_cast<float2*>(h0s + o) = make_float2(h0, h1);
  *reinterpret_cast<float2*>(As + o) = make_float2(A0, A1);
}

// ---------------------------------------------------------------------------
// Kernel 4b: carry scan over chunk summaries.  Per (b, s): hin_0 = 0,
// hin_{c+1} = h0_c + A_c * hin_c.  Stores hin per (b, c, s).
// ---------------------------------------------------------------------------
__global__ __launch_bounds__(256) void scan_phase_b(
    const float* __restrict__ h0s, const float* __restrict__ As,
    float* __restrict__ hins) {
  const int b = blockIdx.x;
  const int s = threadIdx.x;
  float hin = 0.f;
#pragma unroll 8
  for (int c = 0; c < CCH; ++c) {
    const size_t idx = ((size_t)b * CCH + c) * SS + s;
    hins[idx] = hin;
    hin = fmaf(As[idx], hin, h0s[idx]);
  }
}

// ---------------------------------------------------------------------------
// Kernel 4c: chunked scan phase C.  Re-run each chunk with correct carry-in,
// gate by sigmoid(g), write hsg (in-place over ut: same-thread read-first).
// ---------------------------------------------------------------------------
__global__ __launch_bounds__(128) void scan_phase_c(
    const __hip_bfloat16* __restrict__ ut,
    const __hip_bfloat16* __restrict__ dtb,
    const __hip_bfloat16* __restrict__ gz,   // uzg + 512, row stride 768
    const float* __restrict__ hins,
    __hip_bfloat16* __restrict__ hsg) {
  const int bc = blockIdx.x;
  const int b = bc / CCH, c = bc % CCH;
  const int ch = threadIdx.x * 2;
  const size_t rowbase = (size_t)b * LL + (size_t)c * TCH;
  const float2 hv = *reinterpret_cast<const float2*>(hins + (size_t)bc * SS + ch);
  float h0 = hv.x, h1 = hv.y;
#pragma unroll 8
  for (int t = 0; t < TCH; ++t) {
    const size_t row = rowbase + t;
    const ushort2 uu = *reinterpret_cast<const ushort2*>(ut + row * SS + ch);
    const ushort2 dd = *reinterpret_cast<const ushort2*>(dtb + row * SS + ch);
    const ushort2 gg = *reinterpret_cast<const ushort2*>(gz + row * 768 + ch);
    h0 = fmaf(bfu(dd.x), bfu(uu.x) - h0, h0);
    h1 = fmaf(bfu(dd.y), bfu(uu.y) - h1, h1);
    union { ushort2 u; __hip_bfloat16 h[2]; } o;
    o.h[0] = __float2bfloat16(h0 / (1.f + expf(-bfu(gg.x))));
    o.h[1] = __float2bfloat16(h1 / (1.f + expf(-bfu(gg.y))));
    *reinterpret_cast<ushort2*>(hsg + row * SS + ch) = o.u;
  }
}

// ---------------------------------------------------------------------------
extern "C" void kernel_launch(void* const* d_in, const int* in_sizes, int n_in,
                              void* d_out, int out_size, void* d_ws, size_t ws_size,
                              hipStream_t stream) {
  const float* x      = (const float*)d_in[0];
  const float* w_norm = (const float*)d_in[1];
  const float* W_in   = (const float*)d_in[2];
  const float* b_in   = (const float*)d_in[3];
  const float* W_x    = (const float*)d_in[4];
  const float* b_x    = (const float*)d_in[5];
  const float* W_dt   = (const float*)d_in[6];
  const float* b_dt   = (const float*)d_in[7];
  const float* W_out  = (const float*)d_in[8];
  const float* b_out  = (const float*)d_in[9];
  float* out = (float*)d_out;

  // Workspace layout (bf16 buffers). ut/dt alias the dead xn region.
  char* w = (char*)d_ws;
  __hip_bfloat16* xn  = (__hip_bfloat16*)w;                 // NTOK*1024
  __hip_bfloat16* ut  = (__hip_bfloat16*)w;                 // NTOK*256 (after GEMM1)
  __hip_bfloat16* dtb = (__hip_bfloat16*)(w + (size_t)NTOK * SS * 2);
  w += (size_t)NTOK * DD * 2;                               // 64 MiB
  __hip_bfloat16* uzg = (__hip_bfloat16*)w;  w += (size_t)NTOK * 768 * 2;  // 48 MiB
  __hip_bfloat16* WinT  = (__hip_bfloat16*)w;  w += (size_t)768 * DD * 2;
  __hip_bfloat16* WxT   = (__hip_bfloat16*)w;  w += (size_t)SS * SS * 2;
  __hip_bfloat16* WdtT  = (__hip_bfloat16*)w;  w += (size_t)SS * SS * 2;
  __hip_bfloat16* WoutT = (__hip_bfloat16*)w;  w += (size_t)DD * SS * 2;
  float* h0s  = (float*)w;  w += (size_t)BB * CCH * SS * 4;   // 512 KiB
  float* As   = (float*)w;  w += (size_t)BB * CCH * SS * 4;
  float* hins = (float*)w;  w += (size_t)BB * CCH * SS * 4;
  (void)ws_size; (void)n_in; (void)in_sizes; (void)out_size;

  // Stage 0: weight conversion (pre-transposed bf16)
  convT<<<(DD * 768 + 255) / 256, 256, 0, stream>>>(W_in, WinT, DD, 768);
  convT<<<(SS * SS + 255) / 256, 256, 0, stream>>>(W_x, WxT, SS, SS);
  convT<<<(SS * SS + 255) / 256, 256, 0, stream>>>(W_dt, WdtT, SS, SS);
  convT<<<(SS * DD + 255) / 256, 256, 0, stream>>>(W_out, WoutT, SS, DD);

  // Stage 1: RMSNorm -> xn (bf16)
  prep_rms<<<NTOK, 256, 0, stream>>>(x, w_norm, xn);

  // Stage 2: uzg = xn @ W_in + b_in   (M=32768, N=768, K=1024)
  gemm_bf16<0><<<dim3(NTOK / 128, 768 / 128), 256, 0, stream>>>(
      xn, DD, WinT, b_in, uzg, 768, nullptr, NTOK, 768, DD);

  // Stage 3: ut = tanh(u @ W_x + b_x); dt = sigmoid(z @ W_dt + b_dt)
  gemm_bf16<1><<<dim3(NTOK / 128, SS / 128), 256, 0, stream>>>(
      uzg, 768, WxT, b_x, ut, SS, nullptr, NTOK, SS, SS);
  gemm_bf16<2><<<dim3(NTOK / 128, SS / 128), 256, 0, stream>>>(
      uzg + SS, 768, WdtT, b_dt, dtb, SS, nullptr, NTOK, SS, SS);

  // Stage 4: chunked parallel scan + gate (in-place hsg over ut buffer)
  scan_phase_a<<<BB * CCH, 128, 0, stream>>>(ut, dtb, h0s, As);
  scan_phase_b<<<BB, 256, 0, stream>>>(h0s, As, hins);
  scan_phase_c<<<BB * CCH, 128, 0, stream>>>(ut, dtb, uzg + 2 * SS, hins, ut);

  // Stage 5: out = x + hsg @ W_out + b_out  (M=32768, N=1024, K=256)
  gemm_bf16<3><<<dim3(NTOK / 128, DD / 128), 256, 0, stream>>>(
      ut, SS, WoutT, b_out, out, DD, x, NTOK, DD, SS);
}